// Round 13
// baseline (365.766 us; speedup 1.0000x reference)
//
#include <hip/hip_runtime.h>
#include <hip/hip_fp16.h>
#include <math.h>

#define DD 64
#define INV_TEMP 4.0f     // 1 / C_TEMP
#define MAXBINS 1280
#define BINSHIFT 8        // 256 rows per bin
#define CAP 10240         // slots per bin (expected max ~7700)
#define ECAP2 (CAP / 512) // max entries per thread in binB (20, fits VGPRs)
#define ECAP_A 16         // max edges per thread in binA (register staging)
#define COLBITS 18        // max col 150016 < 2^18
#define COLMASK ((1u << COLBITS) - 1)
#define CBSHIFT 14        // column block = 16384 cols = 1 MB of 64B table rows
#define K1 32.0f          // fp8 pre-scale, layer-1 tables
#define K2_OVER_K1 4.0f   // layer-2 table scale ratio (scales cancel in norms)

typedef float v2f __attribute__((ext_vector_type(2)));
typedef _Float16 f16x4v __attribute__((ext_vector_type(4)));
typedef _Float16 f16x8v __attribute__((ext_vector_type(8)));
typedef float f32x4v __attribute__((ext_vector_type(4)));

__device__ __forceinline__ float waveSum(float x) {
#pragma unroll
    for (int off = 32; off > 0; off >>= 1) x += __shfl_xor(x, off, 64);
    return x;
}

__device__ __forceinline__ unsigned packH2(float a, float b) {
    __half2 h = __halves2half2(__float2half_rn(a), __float2half_rn(b));
    return *(unsigned*)&h;
}
__device__ __forceinline__ float2 unpackH2(unsigned u) {
    __half2 h = *(__half2*)&u;
    return __half22float2(h);
}
__device__ __forceinline__ unsigned packFp8x4(float a, float b, float c, float d) {
    int v = __builtin_amdgcn_cvt_pk_fp8_f32(a, b, 0, false);
    v = __builtin_amdgcn_cvt_pk_fp8_f32(c, d, v, true);
    return (unsigned)v;
}

// accumulate one 16B fp8 chunk (16 values) into 8 v2f accumulators
__device__ __forceinline__ void accFp8(uint4 d,
    v2f& a0, v2f& a1, v2f& a2, v2f& a3,
    v2f& a4, v2f& a5, v2f& a6, v2f& a7)
{
    a0 += __builtin_amdgcn_cvt_pk_f32_fp8((int)d.x, false);
    a1 += __builtin_amdgcn_cvt_pk_f32_fp8((int)d.x, true);
    a2 += __builtin_amdgcn_cvt_pk_f32_fp8((int)d.y, false);
    a3 += __builtin_amdgcn_cvt_pk_f32_fp8((int)d.y, true);
    a4 += __builtin_amdgcn_cvt_pk_f32_fp8((int)d.z, false);
    a5 += __builtin_amdgcn_cvt_pk_f32_fp8((int)d.z, true);
    a6 += __builtin_amdgcn_cvt_pk_f32_fp8((int)d.w, false);
    a7 += __builtin_amdgcn_cvt_pk_f32_fp8((int)d.w, true);
}

__device__ __forceinline__ void accH16(uint4 d,
    v2f& a0, v2f& a1, v2f& a2, v2f& a3)
{
    float2 h0 = unpackH2(d.x), h1 = unpackH2(d.y);
    float2 h2 = unpackH2(d.z), h3 = unpackH2(d.w);
    a0[0] += h0.x; a0[1] += h0.y; a1[0] += h1.x; a1[1] += h1.y;
    a2[0] += h2.x; a2[1] += h2.y; a3[0] += h3.x; a3[1] += h3.y;
}

__device__ __forceinline__ void zero4(uint4& d) { d.x = 0; d.y = 0; d.z = 0; d.w = 0; }

// x8 software-pipelined fp8 gather-accumulate (R9/R10: gather passes are
// in-flight-request-bound; x8 slightly beats x4 and both are near the
// gather-miss floor).
__device__ __forceinline__ void gatherFp8(
    const int* __restrict__ csp, int deg,
    const unsigned* __restrict__ tab, int sub,
    v2f& a0, v2f& a1, v2f& a2, v2f& a3,
    v2f& a4, v2f& a5, v2f& a6, v2f& a7)
{
    if (deg <= 0) return;
    int c0 = csp[0];
    int c1 = (1 < deg) ? csp[1] : 0;
    int c2 = (2 < deg) ? csp[2] : 0;
    int c3 = (3 < deg) ? csp[3] : 0;
    int c4 = (4 < deg) ? csp[4] : 0;
    int c5 = (5 < deg) ? csp[5] : 0;
    int c6 = (6 < deg) ? csp[6] : 0;
    int c7 = (7 < deg) ? csp[7] : 0;
    int kc = 0, k = 8;
    while (true) {
        uint4 d0 = *((const uint4*)(tab + (size_t)c0 * 16) + sub);
        uint4 d1 = *((const uint4*)(tab + (size_t)c1 * 16) + sub);
        uint4 d2 = *((const uint4*)(tab + (size_t)c2 * 16) + sub);
        uint4 d3 = *((const uint4*)(tab + (size_t)c3 * 16) + sub);
        uint4 d4 = *((const uint4*)(tab + (size_t)c4 * 16) + sub);
        uint4 d5 = *((const uint4*)(tab + (size_t)c5 * 16) + sub);
        uint4 d6 = *((const uint4*)(tab + (size_t)c6 * 16) + sub);
        uint4 d7 = *((const uint4*)(tab + (size_t)c7 * 16) + sub);
        bool more = k < deg;
        int n0 = 0, n1 = 0, n2 = 0, n3 = 0, n4 = 0, n5 = 0, n6 = 0, n7 = 0;
        if (more) {
            n0 = csp[k];
            n1 = (k + 1 < deg) ? csp[k + 1] : 0;
            n2 = (k + 2 < deg) ? csp[k + 2] : 0;
            n3 = (k + 3 < deg) ? csp[k + 3] : 0;
            n4 = (k + 4 < deg) ? csp[k + 4] : 0;
            n5 = (k + 5 < deg) ? csp[k + 5] : 0;
            n6 = (k + 6 < deg) ? csp[k + 6] : 0;
            n7 = (k + 7 < deg) ? csp[k + 7] : 0;
        }
        if (kc + 1 >= deg) zero4(d1);
        if (kc + 2 >= deg) zero4(d2);
        if (kc + 3 >= deg) zero4(d3);
        if (kc + 4 >= deg) zero4(d4);
        if (kc + 5 >= deg) zero4(d5);
        if (kc + 6 >= deg) zero4(d6);
        if (kc + 7 >= deg) zero4(d7);
        accFp8(d0, a0, a1, a2, a3, a4, a5, a6, a7);
        accFp8(d1, a0, a1, a2, a3, a4, a5, a6, a7);
        accFp8(d2, a0, a1, a2, a3, a4, a5, a6, a7);
        accFp8(d3, a0, a1, a2, a3, a4, a5, a6, a7);
        accFp8(d4, a0, a1, a2, a3, a4, a5, a6, a7);
        accFp8(d5, a0, a1, a2, a3, a4, a5, a6, a7);
        accFp8(d6, a0, a1, a2, a3, a4, a5, a6, a7);
        accFp8(d7, a0, a1, a2, a3, a4, a5, a6, a7);
        if (!more) break;
        c0 = n0; c1 = n1; c2 = n2; c3 = n3;
        c4 = n4; c5 = n5; c6 = n6; c7 = n7;
        kc = k; k += 8;
    }
}

// ------------------------- binned CSR build -------------------------
// Global row space: [0,n1) graph1, [n1,n1+n2) graph2, [n1+n2,+NBv) graph3.
// Bin b owns rows [b*256,(b+1)*256) and region binned[b*CAP .. +CAP).

__device__ __forceinline__ void fetchEdge(
    int i, const int* __restrict__ r1, const int* __restrict__ c1,
    const int* __restrict__ r2, const int* __restrict__ c2,
    const int* __restrict__ r3, const int* __restrict__ c3,
    int E1, int E12, int b2, int b3, int& row, int& col)
{
    if (i < E1)       { row = __builtin_nontemporal_load(&r1[i]);
                        col = __builtin_nontemporal_load(&c1[i]); }
    else if (i < E12) { int j = i - E1;
                        row = b2 + __builtin_nontemporal_load(&r2[j]);
                        col = __builtin_nontemporal_load(&c2[j]); }
    else              { int j = i - E12;
                        row = b3 + __builtin_nontemporal_load(&r3[j]);
                        col = __builtin_nontemporal_load(&c3[j]); }
}

// Single-pass binA: register-stage each thread's <=16 (row,col) pairs during
// the histogram pass, then scatter from registers.
__global__ void __launch_bounds__(1024)
binA_kernel(
    const int* __restrict__ r1, const int* __restrict__ c1,
    const int* __restrict__ r2, const int* __restrict__ c2,
    const int* __restrict__ r3, const int* __restrict__ c3,
    int E1, int E2, int E3, int b2, int b3, int nbins,
    int* __restrict__ binCursor, unsigned* __restrict__ binned,
    int chunk, int Etot)
{
    __shared__ int hist[MAXBINS];
    __shared__ int resv[MAXBINS];
    int t = threadIdx.x;
    for (int b = t; b < nbins; b += 1024) hist[b] = 0;
    __syncthreads();
    int lo = blockIdx.x * chunk;
    int hi = min(lo + chunk, Etot);
    int E12 = E1 + E2;
    int rowR[ECAP_A], colR[ECAP_A];
#pragma unroll
    for (int j = 0; j < ECAP_A; j++) {
        int i = lo + t + (j << 10);
        if (i < hi) {
            int row, col;
            fetchEdge(i, r1, c1, r2, c2, r3, c3, E1, E12, b2, b3, row, col);
            rowR[j] = row; colR[j] = col;
            atomicAdd(&hist[row >> BINSHIFT], 1);
        }
    }
    __syncthreads();
    for (int b = t; b < nbins; b += 1024) {
        int h = hist[b];
        resv[b] = h ? atomicAdd(&binCursor[b], h) : 0;
    }
    __syncthreads();
    for (int b = t; b < nbins; b += 1024) hist[b] = 0;  // becomes scatter cursor
    __syncthreads();
#pragma unroll
    for (int j = 0; j < ECAP_A; j++) {
        int i = lo + t + (j << 10);
        if (i < hi) {
            int row = rowR[j], col = colR[j];
            int b = row >> BINSHIFT;
            int off = atomicAdd(&hist[b], 1);
            unsigned v = ((unsigned)(row & 255) << COLBITS) | (unsigned)col;
            binned[(size_t)b * CAP + resv[b] + off] = v;
        }
    }
}

// Pass B: per-bin counting sort by (row, colBlock) — each row's edge list
// comes out column-block-sorted. rowStart/cnt from scan boundaries.
__global__ void __launch_bounds__(512) binB_kernel(
    unsigned* __restrict__ binned, const int* __restrict__ binCursor,
    int ntot,
    int* __restrict__ cnt, int* __restrict__ rowStart)
{
    __shared__ int hist[4096];   // (localRow<<4) | colBlk
    __shared__ int wtot[8];
    int b = blockIdx.x;
    size_t base = (size_t)b * CAP;
    int len = min(binCursor[b], CAP);
    int rowLo = b << BINSHIFT;
    int t = threadIdx.x;
#pragma unroll
    for (int i = 0; i < 8; i++) hist[t * 8 + i] = 0;
    __syncthreads();

    // phase 1: single global read into registers, keyed histogram in LDS
    unsigned ent[ECAP2];
#pragma unroll
    for (int k = 0; k < ECAP2; k++) {
        int i = t + (k << 9);
        if (i < len) {
            unsigned u = __builtin_nontemporal_load(&binned[base + i]);
            ent[k] = u;
            int key = (int)((u >> COLBITS) << 4) | (int)((u & COLMASK) >> CBSHIFT);
            atomicAdd(&hist[key], 1);
        }
    }
    __syncthreads();

    // exclusive scan over 4096 bins: 8 serial per thread + 512 wave-scan
    int s0, s1, s2, s3, s4, s5, s6, s7;
    int b8 = t * 8;
    s0 = hist[b8];     s1 = hist[b8 + 1]; s2 = hist[b8 + 2]; s3 = hist[b8 + 3];
    s4 = hist[b8 + 4]; s5 = hist[b8 + 5]; s6 = hist[b8 + 6]; s7 = hist[b8 + 7];
    int tot = s0 + s1 + s2 + s3 + s4 + s5 + s6 + s7;
    int lane = t & 63, w = t >> 6;
    int sc = tot;
    for (int off = 1; off < 64; off <<= 1) {
        int u = __shfl_up(sc, off, 64);
        if (lane >= off) sc += u;
    }
    if (lane == 63) wtot[w] = sc;
    __syncthreads();
    int woff = 0;
    for (int i = 0; i < w; i++) woff += wtot[i];
    int run = woff + sc - tot;   // exclusive prefix of this thread's 8 bins
    hist[b8] = run;     run += s0;
    hist[b8 + 1] = run; run += s1;
    hist[b8 + 2] = run; run += s2;
    hist[b8 + 3] = run; run += s3;
    hist[b8 + 4] = run; run += s4;
    hist[b8 + 5] = run; run += s5;
    hist[b8 + 6] = run; run += s6;
    hist[b8 + 7] = run;
    __syncthreads();

    // rowStart/cnt from scan boundaries (row region = 16 consecutive bins)
    int grow = rowLo + t;
    if (t < 256 && grow < ntot) {
        int rs = hist[t << 4];
        int nx = (t == 255) ? len : hist[(t + 1) << 4];
        cnt[grow] = nx - rs;
        rowStart[grow] = (int)base + rs;
    }
    __syncthreads();

    // phase 2: scatter from registers via LDS cursors (in-place, hazard-free)
#pragma unroll
    for (int k = 0; k < ECAP2; k++) {
        int i = t + (k << 9);
        if (i < len) {
            unsigned u = ent[k];
            int key = (int)((u >> COLBITS) << 4) | (int)((u & COLMASK) >> CBSHIFT);
            int p = atomicAdd(&hist[key], 1);
            binned[base + p] = u & COLMASK;
        }
    }
}

// Streaming prep: K1-scaled fp8 layer-1 tables (user rows feed BOTH graphs)
// + fp16 feature copy hfeat[users|items|bundles] so spmm_l2 reads 128B/row
// instead of 256B fp32. NO nontemporal hints (R8 lesson).
__global__ void __launch_bounds__(256) prep_kernel(
    const float* __restrict__ usersF, const float* __restrict__ itemsF,
    const float* __restrict__ bundF, const int* __restrict__ cnt,
    int NUv, int NIv, int NBv, int n1,
    unsigned* __restrict__ g01, unsigned* __restrict__ g02,
    unsigned* __restrict__ hfeat)
{
    int total = (NUv + NIv + NBv) * 16;
    int stride = gridDim.x * blockDim.x;
    for (int idx = blockIdx.x * blockDim.x + threadIdx.x; idx < total; idx += stride) {
        int rl = idx >> 4, pr = idx & 15;
        float4 f;
        if (rl < NUv) {
            f = *((const float4*)(usersF + (size_t)rl * DD) + pr);
            float s1 = K1 / (sqrtf((float)cnt[rl]) + 1e-8f);
            float s2 = K1 / (sqrtf((float)cnt[n1 + rl]) + 1e-8f);
            g01[(size_t)rl * 16 + pr] = packFp8x4(f.x*s1, f.y*s1, f.z*s1, f.w*s1);
            g02[(size_t)rl * 16 + pr] = packFp8x4(f.x*s2, f.y*s2, f.z*s2, f.w*s2);
        } else if (rl < NUv + NIv) {
            int r = rl - NUv;
            f = *((const float4*)(itemsF + (size_t)r * DD) + pr);
            float s = K1 / (sqrtf((float)cnt[NUv + r]) + 1e-8f);
            g01[(size_t)(NUv + r) * 16 + pr] = packFp8x4(f.x*s, f.y*s, f.z*s, f.w*s);
        } else {
            int r = rl - NUv - NIv;
            f = *((const float4*)(bundF + (size_t)r * DD) + pr);
            float s = K1 / (sqrtf((float)cnt[n1 + NUv + r]) + 1e-8f);
            g02[(size_t)(NUv + r) * 16 + pr] = packFp8x4(f.x*s, f.y*s, f.z*s, f.w*s);
        }
        uint2 h;
        h.x = packH2(f.x, f.y);
        h.y = packH2(f.z, f.w);
        *(uint2*)(hfeat + (size_t)rl * 32 + pr * 2) = h;
    }
}

// ------------------------- fused SpMM -------------------------
// Natural row order; 16 rows/wave (4 lanes x 16B per row). x8 pipelined
// gather loop (gatherFp8). Layer 1 (merged graphs 1+2):
// out8 = (K2/K1)*s^2*u (fp8), out16 = u/|u| (fp16)
__global__ void __launch_bounds__(256) spmm_l1(
    const int* __restrict__ rowStart, const int* __restrict__ cnt,
    const int* __restrict__ cs, int n1, int nAll,
    const unsigned* __restrict__ g01, const unsigned* __restrict__ g02,
    unsigned* __restrict__ g11, unsigned* __restrict__ g12,
    __half* __restrict__ nrm11, __half* __restrict__ nrm12)
{
    int lane = threadIdx.x & 63;
    int grp  = lane >> 2;
    int sub  = lane & 3;
    int wave = (blockIdx.x * blockDim.x + threadIdx.x) >> 6;
    int nW   = (gridDim.x * blockDim.x) >> 6;
    for (int g0 = wave * 16; g0 < nAll; g0 += nW * 16) {
        int g = g0 + grp;
        bool valid = g < nAll;
        int gi = valid ? g : nAll - 1;
        int start = rowStart[gi];
        int deg   = valid ? cnt[gi] : 0;
        bool first = gi < n1;
        const unsigned* tab = first ? g01 : g02;
        v2f a0 = {0.f,0.f}, a1 = {0.f,0.f}, a2 = {0.f,0.f}, a3 = {0.f,0.f};
        v2f a4 = {0.f,0.f}, a5 = {0.f,0.f}, a6 = {0.f,0.f}, a7 = {0.f,0.f};
        gatherFp8(cs + start, deg, tab, sub, a0, a1, a2, a3, a4, a5, a6, a7);
        float ns = a0[0]*a0[0] + a0[1]*a0[1] + a1[0]*a1[0] + a1[1]*a1[1]
                 + a2[0]*a2[0] + a2[1]*a2[1] + a3[0]*a3[0] + a3[1]*a3[1]
                 + a4[0]*a4[0] + a4[1]*a4[1] + a5[0]*a5[0] + a5[1]*a5[1]
                 + a6[0]*a6[0] + a6[1]*a6[1] + a7[0]*a7[0] + a7[1]*a7[1];
        ns += __shfl_xor(ns, 1, 64);
        ns += __shfl_xor(ns, 2, 64);
        float inv = 1.0f / fmaxf(sqrtf(ns), 1e-12f);
        float s = 1.0f / (sqrtf((float)deg) + 1e-8f);
        float m = K2_OVER_K1 * s * s;
        if (valid) {
            int r = first ? g : g - n1;
            unsigned* o8p = first ? g11 + (size_t)r * 16
                                  : g12 + (size_t)r * 16;
            __half* o16p = first ? nrm11 + (size_t)r * DD
                                 : nrm12 + (size_t)r * DD;
            uint4 o8;
            o8.x = packFp8x4(a0[0]*m, a0[1]*m, a1[0]*m, a1[1]*m);
            o8.y = packFp8x4(a2[0]*m, a2[1]*m, a3[0]*m, a3[1]*m);
            o8.z = packFp8x4(a4[0]*m, a4[1]*m, a5[0]*m, a5[1]*m);
            o8.w = packFp8x4(a6[0]*m, a6[1]*m, a7[0]*m, a7[1]*m);
            *((uint4*)o8p + sub) = o8;
            uint4 oA, oB;
            oA.x = packH2(a0[0]*inv, a0[1]*inv);
            oA.y = packH2(a1[0]*inv, a1[1]*inv);
            oA.z = packH2(a2[0]*inv, a2[1]*inv);
            oA.w = packH2(a3[0]*inv, a3[1]*inv);
            oB.x = packH2(a4[0]*inv, a4[1]*inv);
            oB.y = packH2(a5[0]*inv, a5[1]*inv);
            oB.z = packH2(a6[0]*inv, a6[1]*inv);
            oB.w = packH2(a7[0]*inv, a7[1]*inv);
            *((uint4*)o16p + sub * 2)     = oA;
            *((uint4*)o16p + sub * 2 + 1) = oB;
        }
    }
}

// Layer 2 (merged graphs 1+2): out16 = f0(fp16) + nrmIn + u/|u| (fp16)
__global__ void __launch_bounds__(256) spmm_l2(
    const int* __restrict__ rowStart, const int* __restrict__ cnt,
    const int* __restrict__ cs, int n1, int nAll, int NUv,
    const unsigned* __restrict__ g11, const unsigned* __restrict__ g12,
    const unsigned* __restrict__ hfeat,
    const __half* __restrict__ nrm11, const __half* __restrict__ nrm12,
    __half* __restrict__ accIL, __half* __restrict__ accBL)
{
    int lane = threadIdx.x & 63;
    int grp  = lane >> 2;
    int sub  = lane & 3;
    int wave = (blockIdx.x * blockDim.x + threadIdx.x) >> 6;
    int nW   = (gridDim.x * blockDim.x) >> 6;
    for (int g0 = wave * 16; g0 < nAll; g0 += nW * 16) {
        int g = g0 + grp;
        bool valid = g < nAll;
        int gi = valid ? g : nAll - 1;
        int start = rowStart[gi];
        int deg   = valid ? cnt[gi] : 0;
        bool first = gi < n1;
        const unsigned* tab = first ? g11 : g12;
        v2f a0 = {0.f,0.f}, a1 = {0.f,0.f}, a2 = {0.f,0.f}, a3 = {0.f,0.f};
        v2f a4 = {0.f,0.f}, a5 = {0.f,0.f}, a6 = {0.f,0.f}, a7 = {0.f,0.f};
        gatherFp8(cs + start, deg, tab, sub, a0, a1, a2, a3, a4, a5, a6, a7);
        float ns = a0[0]*a0[0] + a0[1]*a0[1] + a1[0]*a1[0] + a1[1]*a1[1]
                 + a2[0]*a2[0] + a2[1]*a2[1] + a3[0]*a3[0] + a3[1]*a3[1]
                 + a4[0]*a4[0] + a4[1]*a4[1] + a5[0]*a5[0] + a5[1]*a5[1]
                 + a6[0]*a6[0] + a6[1]*a6[1] + a7[0]*a7[0] + a7[1]*a7[1];
        ns += __shfl_xor(ns, 1, 64);
        ns += __shfl_xor(ns, 2, 64);
        float inv = 1.0f / fmaxf(sqrtf(ns), 1e-12f);
        if (valid) {
            int r = first ? g : g - n1;
            // fp16 feature copy: [users | items | bundles]
            const unsigned* hf =
                first ? hfeat + (size_t)g * 32
                      : ((r < NUv) ? hfeat + (size_t)r * 32
                                   : hfeat + (size_t)(n1 + (r - NUv)) * 32);
            const __half* nrmIn = first ? nrm11 + (size_t)r * DD
                                        : nrm12 + (size_t)r * DD;
            __half* outp = first ? accIL + (size_t)r * DD
                                 : accBL + (size_t)r * DD;
            uint4 fA = *((const uint4*)hf + sub * 2);
            uint4 fB = *((const uint4*)hf + sub * 2 + 1);
            float2 f0 = unpackH2(fA.x), f1 = unpackH2(fA.y);
            float2 f2 = unpackH2(fA.z), f3 = unpackH2(fA.w);
            float2 f4 = unpackH2(fB.x), f5 = unpackH2(fB.y);
            float2 f6 = unpackH2(fB.z), f7 = unpackH2(fB.w);
            uint4 nvA = *((const uint4*)nrmIn + sub * 2);
            uint4 nvB = *((const uint4*)nrmIn + sub * 2 + 1);
            float2 m0 = unpackH2(nvA.x), m1 = unpackH2(nvA.y);
            float2 m2 = unpackH2(nvA.z), m3 = unpackH2(nvA.w);
            float2 m4 = unpackH2(nvB.x), m5 = unpackH2(nvB.y);
            float2 m6 = unpackH2(nvB.z), m7 = unpackH2(nvB.w);
            uint4 oA, oB;
            oA.x = packH2(f0.x + m0.x + a0[0]*inv, f0.y + m0.y + a0[1]*inv);
            oA.y = packH2(f1.x + m1.x + a1[0]*inv, f1.y + m1.y + a1[1]*inv);
            oA.z = packH2(f2.x + m2.x + a2[0]*inv, f2.y + m2.y + a2[1]*inv);
            oA.w = packH2(f3.x + m3.x + a3[0]*inv, f3.y + m3.y + a3[1]*inv);
            oB.x = packH2(f4.x + m4.x + a4[0]*inv, f4.y + m4.y + a4[1]*inv);
            oB.y = packH2(f5.x + m5.x + a5[0]*inv, f5.y + m5.y + a5[1]*inv);
            oB.z = packH2(f6.x + m6.x + a6[0]*inv, f6.y + m6.y + a6[1]*inv);
            oB.w = packH2(f7.x + m7.x + a7[0]*inv, f7.y + m7.y + a7[1]*inv);
            *((uint4*)outp + sub * 2)     = oA;
            *((uint4*)outp + sub * 2 + 1) = oB;
        }
    }
}

// Graph 3 aggregation (fp16 table), 8 rows/wave, pipelined x4:
// out = u/(deg+1e-8)
__global__ void __launch_bounds__(256) spmm_agg(
    const int* __restrict__ rowStart, const int* __restrict__ cnt,
    const int* __restrict__ cs, int rbase,
    const __half* __restrict__ table16, __half* __restrict__ out16, int n)
{
    int lane = threadIdx.x & 63;
    int grp  = lane >> 3;
    int sub  = lane & 7;
    int wave = (blockIdx.x * blockDim.x + threadIdx.x) >> 6;
    int nW   = (gridDim.x * blockDim.x) >> 6;
    for (int r0 = wave * 8; r0 < n; r0 += nW * 8) {
        int r = r0 + grp;
        bool valid = r < n;
        int idx = rbase + (valid ? r : n - 1);
        int start = rowStart[idx];
        int deg   = valid ? cnt[idx] : 0;
        const int* csp = cs + start;
        v2f a0 = {0.f, 0.f}, a1 = {0.f, 0.f}, a2 = {0.f, 0.f}, a3 = {0.f, 0.f};
        if (deg > 0) {
            int c0 = csp[0];
            int c1i = (1 < deg) ? csp[1] : 0;
            int c2i = (2 < deg) ? csp[2] : 0;
            int c3i = (3 < deg) ? csp[3] : 0;
            int kc = 0, k = 4;
            while (true) {
                uint4 d0 = *((const uint4*)(table16 + (size_t)c0 * DD) + sub);
                uint4 d1 = *((const uint4*)(table16 + (size_t)c1i * DD) + sub);
                uint4 d2 = *((const uint4*)(table16 + (size_t)c2i * DD) + sub);
                uint4 d3 = *((const uint4*)(table16 + (size_t)c3i * DD) + sub);
                bool more = k < deg;
                int n0 = 0, n1v = 0, n2v = 0, n3v = 0;
                if (more) {
                    n0  = csp[k];
                    n1v = (k + 1 < deg) ? csp[k + 1] : 0;
                    n2v = (k + 2 < deg) ? csp[k + 2] : 0;
                    n3v = (k + 3 < deg) ? csp[k + 3] : 0;
                }
                if (kc + 1 >= deg) zero4(d1);
                if (kc + 2 >= deg) zero4(d2);
                if (kc + 3 >= deg) zero4(d3);
                accH16(d0, a0, a1, a2, a3);
                accH16(d1, a0, a1, a2, a3);
                accH16(d2, a0, a1, a2, a3);
                accH16(d3, a0, a1, a2, a3);
                if (!more) break;
                c0 = n0; c1i = n1v; c2i = n2v; c3i = n3v;
                kc = k; k += 4;
            }
        }
        float sc2 = 1.0f / ((float)deg + 1e-8f);
        if (valid) {
            uint4 o;
            o.x = packH2(a0[0]*sc2, a0[1]*sc2);
            o.y = packH2(a1[0]*sc2, a1[1]*sc2);
            o.z = packH2(a2[0]*sc2, a2[1]*sc2);
            o.w = packH2(a3[0]*sc2, a3[1]*sc2);
            *((uint4*)(out16 + (size_t)r * DD) + sub) = o;
        }
    }
}

// ------------------------- batch + losses -------------------------

__global__ void batch_kernel(
    const int* __restrict__ users, const int* __restrict__ bundles,
    const __half* __restrict__ IL, const __half* __restrict__ ILb,
    const __half* __restrict__ BL, int NUv,
    __half* __restrict__ pos1, __half* __restrict__ aug1,
    __half* __restrict__ pos2, __half* __restrict__ aug2,
    float* __restrict__ sums, int batch)
{
    int lane = threadIdx.x & 63;
    int wave = (blockIdx.x * blockDim.x + threadIdx.x) >> 6;
    int nW   = (gridDim.x * blockDim.x) >> 6;
    for (int b = wave; b < batch; b += nW) {
        int u   = users[b];
        int bp  = bundles[2 * b];
        int bn  = bundles[2 * b + 1];
        float ilu  = __half2float(IL [(size_t)u * DD + lane]);
        float blu  = __half2float(BL [(size_t)u * DD + lane]);
        float ilb0 = __half2float(ILb[(size_t)bp * DD + lane]);
        float ilb1 = __half2float(ILb[(size_t)bn * DD + lane]);
        float blb0 = __half2float(BL [(size_t)(NUv + bp) * DD + lane]);
        float blb1 = __half2float(BL [(size_t)(NUv + bn) * DD + lane]);
        float d0 = waveSum(ilu * ilb0 + blu * blb0);
        float d1 = waveSum(ilu * ilb1 + blu * blb1);
        float x  = d1 - d0;
        float sp = fmaxf(x, 0.f) + log1pf(expf(-fabsf(x)));
        if (lane == 0) atomicAdd(&sums[0], sp);
        float nilu = sqrtf(waveSum(ilu * ilu));
        float nblu = sqrtf(waveSum(blu * blu));
        float nilb = sqrtf(waveSum(ilb0 * ilb0));
        float nblb = sqrtf(waveSum(blb0 * blb0));
        pos1[(size_t)b * DD + lane] = __float2half(ilu  / fmaxf(nilu, 1e-12f));
        aug1[(size_t)b * DD + lane] = __float2half(blu  / fmaxf(nblu, 1e-12f));
        pos2[(size_t)b * DD + lane] = __float2half(ilb0 / fmaxf(nilb, 1e-12f));
        aug2[(size_t)b * DD + lane] = __float2half(blb0 / fmaxf(nblb, 1e-12f));
    }
}

// load an 8-half MFMA fragment for row `rowp`, K window [k0,k0+32):
// lane's elems cover k = k0 + 4*g + {0..3} and k0 + 16 + 4*g + {0..3}.
// Any consistent lane->K bijection is valid as long as A and B use the SAME
// map (dot product is K-permutation-invariant); only M/N = lane&15 and the
// m89-verified C/D layout (col=lane&15, row=(lane>>4)*4+reg) must hold.
__device__ __forceinline__ f16x8v loadFrag(const __half* rowp, int g, int k0) {
    const _Float16* p = (const _Float16*)rowp;
    f16x4v lo = *(const f16x4v*)(p + k0 + 4 * g);
    f16x4v hi = *(const f16x4v*)(p + k0 + 16 + 4 * g);
    f16x8v r;
    r[0] = lo[0]; r[1] = lo[1]; r[2] = lo[2]; r[3] = lo[3];
    r[4] = hi[0]; r[5] = hi[1]; r[6] = hi[2]; r[7] = hi[3];
    return r;
}

// MFMA contrastive-loss: T = (P . A^T) * INV_TEMP per view; accumulates
// rowsum(exp(T)) into S and writes diag into Dg. One wave owns a 16-row
// strip and sweeps a j-chunk in 16x16 tiles (2x mfma_f32_16x16x32_f16).
// No LDS; pos/aug are L2-resident fp16.
__global__ void __launch_bounds__(256) closs_kernel(
    const __half* __restrict__ pos1, const __half* __restrict__ aug1,
    const __half* __restrict__ pos2, const __half* __restrict__ aug2,
    float* __restrict__ S, float* __restrict__ Dg, int batch, int jChunk)
{
    int view = blockIdx.z;
    const __half* pos = view ? pos2 : pos1;
    const __half* aug = view ? aug2 : aug1;
    int w = threadIdx.x >> 6, lane = threadIdx.x & 63;
    int g = lane >> 4, c = lane & 15;
    int i0 = blockIdx.x * 64 + w * 16;
    int jBeg = blockIdx.y * jChunk;
    int jEnd = min(jBeg + jChunk, batch);
    int ra = min(i0 + c, batch - 1);
    const __half* prow = pos + (size_t)ra * DD;
    f16x8v aF0 = loadFrag(prow, g, 0);
    f16x8v aF1 = loadFrag(prow, g, 32);
    float rs0 = 0.f, rs1 = 0.f, rs2 = 0.f, rs3 = 0.f;
    for (int j0 = jBeg; j0 < jEnd; j0 += 16) {
        int rb = min(j0 + c, batch - 1);
        const __half* arow = aug + (size_t)rb * DD;
        f16x8v bF0 = loadFrag(arow, g, 0);
        f16x8v bF1 = loadFrag(arow, g, 32);
        f32x4v acc = {0.f, 0.f, 0.f, 0.f};
        acc = __builtin_amdgcn_mfma_f32_16x16x32_f16(aF0, bF0, acc, 0, 0, 0);
        acc = __builtin_amdgcn_mfma_f32_16x16x32_f16(aF1, bF1, acc, 0, 0, 0);
        int gj = j0 + c;
#pragma unroll
        for (int e = 0; e < 4; e++) {
            int gi = i0 + g * 4 + e;
            float t = acc[e] * INV_TEMP;
            float ex = (gi < batch && gj < batch) ? __expf(t) : 0.f;
            if (gi == gj && gi < batch) Dg[view * batch + gi] = t;
            ex += __shfl_xor(ex, 1, 64);
            ex += __shfl_xor(ex, 2, 64);
            ex += __shfl_xor(ex, 4, 64);
            ex += __shfl_xor(ex, 8, 64);
            if (e == 0) rs0 += ex;
            else if (e == 1) rs1 += ex;
            else if (e == 2) rs2 += ex;
            else rs3 += ex;
        }
    }
    if (c == 0) {
        int base = view * batch + i0 + g * 4;
        if (base - view * batch + 0 < batch) atomicAdd(&S[base + 0], rs0);
        if (base - view * batch + 1 < batch) atomicAdd(&S[base + 1], rs1);
        if (base - view * batch + 2 < batch) atomicAdd(&S[base + 2], rs2);
        if (base - view * batch + 3 < batch) atomicAdd(&S[base + 3], rs3);
    }
}

__global__ void closs_finish(const float* __restrict__ S, const float* __restrict__ Dg,
                             const float* __restrict__ sums,
                             float* __restrict__ out, int batch, float invB)
{
    int tid = threadIdx.x;
    __shared__ float wsm[2][4];
    float tot[2];
#pragma unroll
    for (int m = 0; m < 2; m++) {
        float local = 0.f;
        for (int i = tid; i < batch; i += blockDim.x)
            local += logf(S[m * batch + i]) - Dg[m * batch + i];
        local = waveSum(local);
        if ((tid & 63) == 0) wsm[m][tid >> 6] = local;
    }
    __syncthreads();
    if (tid == 0) {
#pragma unroll
        for (int m = 0; m < 2; m++)
            tot[m] = wsm[m][0] + wsm[m][1] + wsm[m][2] + wsm[m][3];
        out[0] = sums[0] * invB;
        out[1] = 0.5f * (tot[0] + tot[1]) * invB;
    }
}

// ------------------------- driver -------------------------

extern "C" void kernel_launch(void* const* d_in, const int* in_sizes, int n_in,
                              void* d_out, int out_size, void* d_ws, size_t ws_size,
                              hipStream_t stream)
{
    const float* usersF = (const float*)d_in[0];
    const float* itemsF = (const float*)d_in[1];
    const float* bundF  = (const float*)d_in[2];
    const int*   il_row = (const int*)d_in[3];
    const int*   il_col = (const int*)d_in[4];
    const int*   bl_row = (const int*)d_in[6];
    const int*   bl_col = (const int*)d_in[7];
    const int*   agg_row = (const int*)d_in[9];
    const int*   agg_col = (const int*)d_in[10];
    const int*   users   = (const int*)d_in[12];
    const int*   bundles = (const int*)d_in[13];

    const int NUv = in_sizes[0] / DD;
    const int NIv = in_sizes[1] / DD;
    const int NBv = in_sizes[2] / DD;
    const int E1 = in_sizes[3], E2 = in_sizes[6], E3 = in_sizes[9];
    const int batch = in_sizes[12];
    const int n1 = NUv + NIv;
    const int n2 = NUv + NBv;
    const int ntot = n1 + n2 + NBv;
    const int Etot = E1 + E2 + E3;
    const int nbins = (ntot + 255) >> BINSHIFT;

    float* ws = (float*)d_ws;
    size_t off = 0;
    float* sums = ws + off;      off += 16;
    float* S    = ws + off;      off += (size_t)2 * batch;
    float* Dg   = ws + off;      off += (size_t)2 * batch;
    int*   cnt  = (int*)(ws + off);      off += (size_t)ntot;
    int*   rowStart = (int*)(ws + off);  off += (size_t)ntot;
    int*   binCursor = (int*)(ws + off); off += MAXBINS;
    off = (off + 3) & ~(size_t)3;     // 16B align for fp8 tables (uint4 gathers)
    unsigned* binned = (unsigned*)(ws + off); off += (size_t)nbins * CAP;
    unsigned* g01 = (unsigned*)(ws + off); off += (size_t)n1 * 16;
    unsigned* g11 = (unsigned*)(ws + off); off += (size_t)n1 * 16;
    unsigned* g02 = (unsigned*)(ws + off); off += (size_t)n2 * 16;
    unsigned* g12 = (unsigned*)(ws + off); off += (size_t)n2 * 16;
    unsigned* hfeat = (unsigned*)(ws + off); off += (size_t)(n1 + NBv) * 32;
    off = (off + 3) & ~(size_t)3;     // 16B align for half tables
    __half* hbase = (__half*)(ws + off);
    size_t hoff = 0;
    __half* nrm11 = hbase + hoff;  hoff += (size_t)n1 * DD;
    __half* accIL = hbase + hoff;  hoff += (size_t)n1 * DD;
    __half* nrm12 = hbase + hoff;  hoff += (size_t)n2 * DD;
    __half* accBL = hbase + hoff;  hoff += (size_t)n2 * DD;
    __half* ILb   = hbase + hoff;  hoff += (size_t)NBv * DD;
    __half* pos1  = hbase + hoff;  hoff += (size_t)batch * DD;
    __half* aug1  = hbase + hoff;  hoff += (size_t)batch * DD;
    __half* pos2  = hbase + hoff;  hoff += (size_t)batch * DD;
    __half* aug2  = hbase + hoff;  hoff += (size_t)batch * DD;
    (void)ws_size;

    hipMemsetAsync(sums, 0, 16 * sizeof(float), stream);
    hipMemsetAsync(S, 0, (size_t)2 * batch * sizeof(float), stream);
    hipMemsetAsync(binCursor, 0, MAXBINS * sizeof(int), stream);

    // ---- binned CSR build (single-pass binA; column-block-sorted binB) ----
    int nA = (Etot + ECAP_A * 1024 - 1) / (ECAP_A * 1024);
    if (nA < 256) nA = 256;
    int chunk = (Etot + nA - 1) / nA;
    binA_kernel<<<nA, 1024, 0, stream>>>(
        il_row, il_col, bl_row, bl_col, agg_row, agg_col,
        E1, E2, E3, n1, n1 + n2, nbins, binCursor, binned, chunk, Etot);
    binB_kernel<<<nbins, 512, 0, stream>>>(
        binned, binCursor, ntot, cnt, rowStart);

    // ---- streaming prep: fp8 tables + fp16 feature copy (needs cnt) ----
    prep_kernel<<<2048, 256, 0, stream>>>(
        usersF, itemsF, bundF, cnt, NUv, NIv, NBv, n1, g01, g02, hfeat);

    const int* cs = (const int*)binned;
    const int nAll = n1 + n2;

    // 16 rows per wave, 4 waves per block -> 64 rows per block
    auto grid16 = [](int n) { return (n + 63) / 64; };
    auto grid8  = [](int n) { return (n + 31) / 32; };

    // ---- layer 1 (graphs 1+2 merged) ----
    spmm_l1<<<grid16(nAll), 256, 0, stream>>>(
        rowStart, cnt, cs, n1, nAll, g01, g02, g11, g12, nrm11, nrm12);

    // ---- layer 2 (graphs 1+2 merged) ----
    spmm_l2<<<grid16(nAll), 256, 0, stream>>>(
        rowStart, cnt, cs, n1, nAll, NUv, g11, g12,
        hfeat, nrm11, nrm12, accIL, accBL);

    // ---- bundle rep from items (graph 3, fp16 table) ----
    spmm_agg<<<grid8(NBv), 256, 0, stream>>>(
        rowStart, cnt, cs, n1 + n2, accIL + (size_t)NUv * DD, ILb, NBv);

    // ---- batch: BPR + normalized fp16 gathers ----
    batch_kernel<<<(batch + 3) / 4, 256, 0, stream>>>(
        users, bundles, accIL, ILb, accBL, NUv,
        pos1, aug1, pos2, aug2, sums, batch);

    // ---- contrastive loss (MFMA) ----
    const int yChunks = 4;
    int jChunk = ((batch + yChunks * 16 - 1) / (yChunks * 16)) * 16;
    dim3 cg2((batch + 63) / 64, yChunks, 2);
    closs_kernel<<<cg2, 256, 0, stream>>>(pos1, aug1, pos2, aug2, S, Dg, batch, jChunk);
    closs_finish<<<1, 256, 0, stream>>>(S, Dg, sums, (float*)d_out, batch,
                                        1.0f / (float)batch);
}

// Round 14
// 359.272 us; speedup vs baseline: 1.0181x; 1.0181x over previous
//
#include <hip/hip_runtime.h>
#include <hip/hip_fp16.h>
#include <math.h>

#define DD 64
#define INV_TEMP 4.0f     // 1 / C_TEMP
#define MAXBINS 1280
#define BINSHIFT 8        // 256 rows per bin
#define CAP 10240         // slots per bin (expected max ~7700)
#define ECAP2 (CAP / 512) // max entries per thread in binB (20, fits VGPRs)
#define ECAP_A 16         // max edges per thread in binA (register staging)
#define COLBITS 18        // max col 150016 < 2^18
#define COLMASK ((1u << COLBITS) - 1)
#define CBSHIFT 14        // column block = 16384 cols = 1 MB of 64B table rows
#define K1 32.0f          // fp8 pre-scale, layer-1 tables
#define K2_OVER_K1 4.0f   // layer-2 table scale ratio (scales cancel in norms)

typedef float v2f __attribute__((ext_vector_type(2)));

__device__ __forceinline__ float waveSum(float x) {
#pragma unroll
    for (int off = 32; off > 0; off >>= 1) x += __shfl_xor(x, off, 64);
    return x;
}

__device__ __forceinline__ unsigned packH2(float a, float b) {
    __half2 h = __halves2half2(__float2half_rn(a), __float2half_rn(b));
    return *(unsigned*)&h;
}
__device__ __forceinline__ float2 unpackH2(unsigned u) {
    __half2 h = *(__half2*)&u;
    return __half22float2(h);
}
__device__ __forceinline__ unsigned packFp8x4(float a, float b, float c, float d) {
    int v = __builtin_amdgcn_cvt_pk_fp8_f32(a, b, 0, false);
    v = __builtin_amdgcn_cvt_pk_fp8_f32(c, d, v, true);
    return (unsigned)v;
}

// accumulate one 16B fp8 chunk (16 values) into 8 v2f accumulators
__device__ __forceinline__ void accFp8(uint4 d,
    v2f& a0, v2f& a1, v2f& a2, v2f& a3,
    v2f& a4, v2f& a5, v2f& a6, v2f& a7)
{
    a0 += __builtin_amdgcn_cvt_pk_f32_fp8((int)d.x, false);
    a1 += __builtin_amdgcn_cvt_pk_f32_fp8((int)d.x, true);
    a2 += __builtin_amdgcn_cvt_pk_f32_fp8((int)d.y, false);
    a3 += __builtin_amdgcn_cvt_pk_f32_fp8((int)d.y, true);
    a4 += __builtin_amdgcn_cvt_pk_f32_fp8((int)d.z, false);
    a5 += __builtin_amdgcn_cvt_pk_f32_fp8((int)d.z, true);
    a6 += __builtin_amdgcn_cvt_pk_f32_fp8((int)d.w, false);
    a7 += __builtin_amdgcn_cvt_pk_f32_fp8((int)d.w, true);
}

__device__ __forceinline__ void accH16(uint4 d,
    v2f& a0, v2f& a1, v2f& a2, v2f& a3)
{
    float2 h0 = unpackH2(d.x), h1 = unpackH2(d.y);
    float2 h2 = unpackH2(d.z), h3 = unpackH2(d.w);
    a0[0] += h0.x; a0[1] += h0.y; a1[0] += h1.x; a1[1] += h1.y;
    a2[0] += h2.x; a2[1] += h2.y; a3[0] += h3.x; a3[1] += h3.y;
}

__device__ __forceinline__ void zero4(uint4& d) { d.x = 0; d.y = 0; d.z = 0; d.w = 0; }

// x8 software-pipelined fp8 gather-accumulate (R9/R10: gather passes are
// in-flight-request-bound; x8 slightly beats x4 and both are near the
// gather-miss floor).
__device__ __forceinline__ void gatherFp8(
    const int* __restrict__ csp, int deg,
    const unsigned* __restrict__ tab, int sub,
    v2f& a0, v2f& a1, v2f& a2, v2f& a3,
    v2f& a4, v2f& a5, v2f& a6, v2f& a7)
{
    if (deg <= 0) return;
    int c0 = csp[0];
    int c1 = (1 < deg) ? csp[1] : 0;
    int c2 = (2 < deg) ? csp[2] : 0;
    int c3 = (3 < deg) ? csp[3] : 0;
    int c4 = (4 < deg) ? csp[4] : 0;
    int c5 = (5 < deg) ? csp[5] : 0;
    int c6 = (6 < deg) ? csp[6] : 0;
    int c7 = (7 < deg) ? csp[7] : 0;
    int kc = 0, k = 8;
    while (true) {
        uint4 d0 = *((const uint4*)(tab + (size_t)c0 * 16) + sub);
        uint4 d1 = *((const uint4*)(tab + (size_t)c1 * 16) + sub);
        uint4 d2 = *((const uint4*)(tab + (size_t)c2 * 16) + sub);
        uint4 d3 = *((const uint4*)(tab + (size_t)c3 * 16) + sub);
        uint4 d4 = *((const uint4*)(tab + (size_t)c4 * 16) + sub);
        uint4 d5 = *((const uint4*)(tab + (size_t)c5 * 16) + sub);
        uint4 d6 = *((const uint4*)(tab + (size_t)c6 * 16) + sub);
        uint4 d7 = *((const uint4*)(tab + (size_t)c7 * 16) + sub);
        bool more = k < deg;
        int n0 = 0, n1 = 0, n2 = 0, n3 = 0, n4 = 0, n5 = 0, n6 = 0, n7 = 0;
        if (more) {
            n0 = csp[k];
            n1 = (k + 1 < deg) ? csp[k + 1] : 0;
            n2 = (k + 2 < deg) ? csp[k + 2] : 0;
            n3 = (k + 3 < deg) ? csp[k + 3] : 0;
            n4 = (k + 4 < deg) ? csp[k + 4] : 0;
            n5 = (k + 5 < deg) ? csp[k + 5] : 0;
            n6 = (k + 6 < deg) ? csp[k + 6] : 0;
            n7 = (k + 7 < deg) ? csp[k + 7] : 0;
        }
        if (kc + 1 >= deg) zero4(d1);
        if (kc + 2 >= deg) zero4(d2);
        if (kc + 3 >= deg) zero4(d3);
        if (kc + 4 >= deg) zero4(d4);
        if (kc + 5 >= deg) zero4(d5);
        if (kc + 6 >= deg) zero4(d6);
        if (kc + 7 >= deg) zero4(d7);
        accFp8(d0, a0, a1, a2, a3, a4, a5, a6, a7);
        accFp8(d1, a0, a1, a2, a3, a4, a5, a6, a7);
        accFp8(d2, a0, a1, a2, a3, a4, a5, a6, a7);
        accFp8(d3, a0, a1, a2, a3, a4, a5, a6, a7);
        accFp8(d4, a0, a1, a2, a3, a4, a5, a6, a7);
        accFp8(d5, a0, a1, a2, a3, a4, a5, a6, a7);
        accFp8(d6, a0, a1, a2, a3, a4, a5, a6, a7);
        accFp8(d7, a0, a1, a2, a3, a4, a5, a6, a7);
        if (!more) break;
        c0 = n0; c1 = n1; c2 = n2; c3 = n3;
        c4 = n4; c5 = n5; c6 = n6; c7 = n7;
        kc = k; k += 8;
    }
}

// ------------------------- binned CSR build -------------------------
// Global row space: [0,n1) graph1, [n1,n1+n2) graph2, [n1+n2,+NBv) graph3.
// Bin b owns rows [b*256,(b+1)*256) and region binned[b*CAP .. +CAP).

__device__ __forceinline__ void fetchEdge(
    int i, const int* __restrict__ r1, const int* __restrict__ c1,
    const int* __restrict__ r2, const int* __restrict__ c2,
    const int* __restrict__ r3, const int* __restrict__ c3,
    int E1, int E12, int b2, int b3, int& row, int& col)
{
    if (i < E1)       { row = __builtin_nontemporal_load(&r1[i]);
                        col = __builtin_nontemporal_load(&c1[i]); }
    else if (i < E12) { int j = i - E1;
                        row = b2 + __builtin_nontemporal_load(&r2[j]);
                        col = __builtin_nontemporal_load(&c2[j]); }
    else              { int j = i - E12;
                        row = b3 + __builtin_nontemporal_load(&r3[j]);
                        col = __builtin_nontemporal_load(&c3[j]); }
}

// Single-pass binA: register-stage each thread's <=16 (row,col) pairs during
// the histogram pass, then scatter from registers.
__global__ void __launch_bounds__(1024)
binA_kernel(
    const int* __restrict__ r1, const int* __restrict__ c1,
    const int* __restrict__ r2, const int* __restrict__ c2,
    const int* __restrict__ r3, const int* __restrict__ c3,
    int E1, int E2, int E3, int b2, int b3, int nbins,
    int* __restrict__ binCursor, unsigned* __restrict__ binned,
    int chunk, int Etot)
{
    __shared__ int hist[MAXBINS];
    __shared__ int resv[MAXBINS];
    int t = threadIdx.x;
    for (int b = t; b < nbins; b += 1024) hist[b] = 0;
    __syncthreads();
    int lo = blockIdx.x * chunk;
    int hi = min(lo + chunk, Etot);
    int E12 = E1 + E2;
    int rowR[ECAP_A], colR[ECAP_A];
#pragma unroll
    for (int j = 0; j < ECAP_A; j++) {
        int i = lo + t + (j << 10);
        if (i < hi) {
            int row, col;
            fetchEdge(i, r1, c1, r2, c2, r3, c3, E1, E12, b2, b3, row, col);
            rowR[j] = row; colR[j] = col;
            atomicAdd(&hist[row >> BINSHIFT], 1);
        }
    }
    __syncthreads();
    for (int b = t; b < nbins; b += 1024) {
        int h = hist[b];
        resv[b] = h ? atomicAdd(&binCursor[b], h) : 0;
    }
    __syncthreads();
    for (int b = t; b < nbins; b += 1024) hist[b] = 0;  // becomes scatter cursor
    __syncthreads();
#pragma unroll
    for (int j = 0; j < ECAP_A; j++) {
        int i = lo + t + (j << 10);
        if (i < hi) {
            int row = rowR[j], col = colR[j];
            int b = row >> BINSHIFT;
            int off = atomicAdd(&hist[b], 1);
            unsigned v = ((unsigned)(row & 255) << COLBITS) | (unsigned)col;
            binned[(size_t)b * CAP + resv[b] + off] = v;
        }
    }
}

// Pass B: per-bin counting sort by (row, colBlock) — each row's edge list
// comes out column-block-sorted. rowStart/cnt from scan boundaries.
__global__ void __launch_bounds__(512) binB_kernel(
    unsigned* __restrict__ binned, const int* __restrict__ binCursor,
    int ntot,
    int* __restrict__ cnt, int* __restrict__ rowStart)
{
    __shared__ int hist[4096];   // (localRow<<4) | colBlk
    __shared__ int wtot[8];
    int b = blockIdx.x;
    size_t base = (size_t)b * CAP;
    int len = min(binCursor[b], CAP);
    int rowLo = b << BINSHIFT;
    int t = threadIdx.x;
#pragma unroll
    for (int i = 0; i < 8; i++) hist[t * 8 + i] = 0;
    __syncthreads();

    // phase 1: single global read into registers, keyed histogram in LDS
    unsigned ent[ECAP2];
#pragma unroll
    for (int k = 0; k < ECAP2; k++) {
        int i = t + (k << 9);
        if (i < len) {
            unsigned u = __builtin_nontemporal_load(&binned[base + i]);
            ent[k] = u;
            int key = (int)((u >> COLBITS) << 4) | (int)((u & COLMASK) >> CBSHIFT);
            atomicAdd(&hist[key], 1);
        }
    }
    __syncthreads();

    // exclusive scan over 4096 bins: 8 serial per thread + 512 wave-scan
    int s0, s1, s2, s3, s4, s5, s6, s7;
    int b8 = t * 8;
    s0 = hist[b8];     s1 = hist[b8 + 1]; s2 = hist[b8 + 2]; s3 = hist[b8 + 3];
    s4 = hist[b8 + 4]; s5 = hist[b8 + 5]; s6 = hist[b8 + 6]; s7 = hist[b8 + 7];
    int tot = s0 + s1 + s2 + s3 + s4 + s5 + s6 + s7;
    int lane = t & 63, w = t >> 6;
    int sc = tot;
    for (int off = 1; off < 64; off <<= 1) {
        int u = __shfl_up(sc, off, 64);
        if (lane >= off) sc += u;
    }
    if (lane == 63) wtot[w] = sc;
    __syncthreads();
    int woff = 0;
    for (int i = 0; i < w; i++) woff += wtot[i];
    int run = woff + sc - tot;   // exclusive prefix of this thread's 8 bins
    hist[b8] = run;     run += s0;
    hist[b8 + 1] = run; run += s1;
    hist[b8 + 2] = run; run += s2;
    hist[b8 + 3] = run; run += s3;
    hist[b8 + 4] = run; run += s4;
    hist[b8 + 5] = run; run += s5;
    hist[b8 + 6] = run; run += s6;
    hist[b8 + 7] = run;
    __syncthreads();

    // rowStart/cnt from scan boundaries (row region = 16 consecutive bins)
    int grow = rowLo + t;
    if (t < 256 && grow < ntot) {
        int rs = hist[t << 4];
        int nx = (t == 255) ? len : hist[(t + 1) << 4];
        cnt[grow] = nx - rs;
        rowStart[grow] = (int)base + rs;
    }
    __syncthreads();

    // phase 2: scatter from registers via LDS cursors (in-place, hazard-free)
#pragma unroll
    for (int k = 0; k < ECAP2; k++) {
        int i = t + (k << 9);
        if (i < len) {
            unsigned u = ent[k];
            int key = (int)((u >> COLBITS) << 4) | (int)((u & COLMASK) >> CBSHIFT);
            int p = atomicAdd(&hist[key], 1);
            binned[base + p] = u & COLMASK;
        }
    }
}

// Streaming prep: K1-scaled fp8 layer-1 tables (user rows feed BOTH graphs)
// + fp16 feature copy hfeat[users|items|bundles] so spmm_l2 reads 128B/row
// instead of 256B fp32. NO nontemporal hints (R8 lesson).
__global__ void __launch_bounds__(256) prep_kernel(
    const float* __restrict__ usersF, const float* __restrict__ itemsF,
    const float* __restrict__ bundF, const int* __restrict__ cnt,
    int NUv, int NIv, int NBv, int n1,
    unsigned* __restrict__ g01, unsigned* __restrict__ g02,
    unsigned* __restrict__ hfeat)
{
    int total = (NUv + NIv + NBv) * 16;
    int stride = gridDim.x * blockDim.x;
    for (int idx = blockIdx.x * blockDim.x + threadIdx.x; idx < total; idx += stride) {
        int rl = idx >> 4, pr = idx & 15;
        float4 f;
        if (rl < NUv) {
            f = *((const float4*)(usersF + (size_t)rl * DD) + pr);
            float s1 = K1 / (sqrtf((float)cnt[rl]) + 1e-8f);
            float s2 = K1 / (sqrtf((float)cnt[n1 + rl]) + 1e-8f);
            g01[(size_t)rl * 16 + pr] = packFp8x4(f.x*s1, f.y*s1, f.z*s1, f.w*s1);
            g02[(size_t)rl * 16 + pr] = packFp8x4(f.x*s2, f.y*s2, f.z*s2, f.w*s2);
        } else if (rl < NUv + NIv) {
            int r = rl - NUv;
            f = *((const float4*)(itemsF + (size_t)r * DD) + pr);
            float s = K1 / (sqrtf((float)cnt[NUv + r]) + 1e-8f);
            g01[(size_t)(NUv + r) * 16 + pr] = packFp8x4(f.x*s, f.y*s, f.z*s, f.w*s);
        } else {
            int r = rl - NUv - NIv;
            f = *((const float4*)(bundF + (size_t)r * DD) + pr);
            float s = K1 / (sqrtf((float)cnt[n1 + NUv + r]) + 1e-8f);
            g02[(size_t)(NUv + r) * 16 + pr] = packFp8x4(f.x*s, f.y*s, f.z*s, f.w*s);
        }
        uint2 h;
        h.x = packH2(f.x, f.y);
        h.y = packH2(f.z, f.w);
        *(uint2*)(hfeat + (size_t)rl * 32 + pr * 2) = h;
    }
}

// ------------------------- fused SpMM -------------------------
// Natural row order; 16 rows/wave (4 lanes x 16B per row). x8 pipelined
// gather loop (gatherFp8). Layer 1 (merged graphs 1+2):
// out8 = (K2/K1)*s^2*u (fp8), out16 = u/|u| (fp16)
__global__ void __launch_bounds__(256) spmm_l1(
    const int* __restrict__ rowStart, const int* __restrict__ cnt,
    const int* __restrict__ cs, int n1, int nAll,
    const unsigned* __restrict__ g01, const unsigned* __restrict__ g02,
    unsigned* __restrict__ g11, unsigned* __restrict__ g12,
    __half* __restrict__ nrm11, __half* __restrict__ nrm12)
{
    int lane = threadIdx.x & 63;
    int grp  = lane >> 2;
    int sub  = lane & 3;
    int wave = (blockIdx.x * blockDim.x + threadIdx.x) >> 6;
    int nW   = (gridDim.x * blockDim.x) >> 6;
    for (int g0 = wave * 16; g0 < nAll; g0 += nW * 16) {
        int g = g0 + grp;
        bool valid = g < nAll;
        int gi = valid ? g : nAll - 1;
        int start = rowStart[gi];
        int deg   = valid ? cnt[gi] : 0;
        bool first = gi < n1;
        const unsigned* tab = first ? g01 : g02;
        v2f a0 = {0.f,0.f}, a1 = {0.f,0.f}, a2 = {0.f,0.f}, a3 = {0.f,0.f};
        v2f a4 = {0.f,0.f}, a5 = {0.f,0.f}, a6 = {0.f,0.f}, a7 = {0.f,0.f};
        gatherFp8(cs + start, deg, tab, sub, a0, a1, a2, a3, a4, a5, a6, a7);
        float ns = a0[0]*a0[0] + a0[1]*a0[1] + a1[0]*a1[0] + a1[1]*a1[1]
                 + a2[0]*a2[0] + a2[1]*a2[1] + a3[0]*a3[0] + a3[1]*a3[1]
                 + a4[0]*a4[0] + a4[1]*a4[1] + a5[0]*a5[0] + a5[1]*a5[1]
                 + a6[0]*a6[0] + a6[1]*a6[1] + a7[0]*a7[0] + a7[1]*a7[1];
        ns += __shfl_xor(ns, 1, 64);
        ns += __shfl_xor(ns, 2, 64);
        float inv = 1.0f / fmaxf(sqrtf(ns), 1e-12f);
        float s = 1.0f / (sqrtf((float)deg) + 1e-8f);
        float m = K2_OVER_K1 * s * s;
        if (valid) {
            int r = first ? g : g - n1;
            unsigned* o8p = first ? g11 + (size_t)r * 16
                                  : g12 + (size_t)r * 16;
            __half* o16p = first ? nrm11 + (size_t)r * DD
                                 : nrm12 + (size_t)r * DD;
            uint4 o8;
            o8.x = packFp8x4(a0[0]*m, a0[1]*m, a1[0]*m, a1[1]*m);
            o8.y = packFp8x4(a2[0]*m, a2[1]*m, a3[0]*m, a3[1]*m);
            o8.z = packFp8x4(a4[0]*m, a4[1]*m, a5[0]*m, a5[1]*m);
            o8.w = packFp8x4(a6[0]*m, a6[1]*m, a7[0]*m, a7[1]*m);
            *((uint4*)o8p + sub) = o8;
            uint4 oA, oB;
            oA.x = packH2(a0[0]*inv, a0[1]*inv);
            oA.y = packH2(a1[0]*inv, a1[1]*inv);
            oA.z = packH2(a2[0]*inv, a2[1]*inv);
            oA.w = packH2(a3[0]*inv, a3[1]*inv);
            oB.x = packH2(a4[0]*inv, a4[1]*inv);
            oB.y = packH2(a5[0]*inv, a5[1]*inv);
            oB.z = packH2(a6[0]*inv, a6[1]*inv);
            oB.w = packH2(a7[0]*inv, a7[1]*inv);
            *((uint4*)o16p + sub * 2)     = oA;
            *((uint4*)o16p + sub * 2 + 1) = oB;
        }
    }
}

// Layer 2 (merged graphs 1+2): out16 = f0(fp16) + nrmIn + u/|u| (fp16)
__global__ void __launch_bounds__(256) spmm_l2(
    const int* __restrict__ rowStart, const int* __restrict__ cnt,
    const int* __restrict__ cs, int n1, int nAll, int NUv,
    const unsigned* __restrict__ g11, const unsigned* __restrict__ g12,
    const unsigned* __restrict__ hfeat,
    const __half* __restrict__ nrm11, const __half* __restrict__ nrm12,
    __half* __restrict__ accIL, __half* __restrict__ accBL)
{
    int lane = threadIdx.x & 63;
    int grp  = lane >> 2;
    int sub  = lane & 3;
    int wave = (blockIdx.x * blockDim.x + threadIdx.x) >> 6;
    int nW   = (gridDim.x * blockDim.x) >> 6;
    for (int g0 = wave * 16; g0 < nAll; g0 += nW * 16) {
        int g = g0 + grp;
        bool valid = g < nAll;
        int gi = valid ? g : nAll - 1;
        int start = rowStart[gi];
        int deg   = valid ? cnt[gi] : 0;
        bool first = gi < n1;
        const unsigned* tab = first ? g11 : g12;
        v2f a0 = {0.f,0.f}, a1 = {0.f,0.f}, a2 = {0.f,0.f}, a3 = {0.f,0.f};
        v2f a4 = {0.f,0.f}, a5 = {0.f,0.f}, a6 = {0.f,0.f}, a7 = {0.f,0.f};
        gatherFp8(cs + start, deg, tab, sub, a0, a1, a2, a3, a4, a5, a6, a7);
        float ns = a0[0]*a0[0] + a0[1]*a0[1] + a1[0]*a1[0] + a1[1]*a1[1]
                 + a2[0]*a2[0] + a2[1]*a2[1] + a3[0]*a3[0] + a3[1]*a3[1]
                 + a4[0]*a4[0] + a4[1]*a4[1] + a5[0]*a5[0] + a5[1]*a5[1]
                 + a6[0]*a6[0] + a6[1]*a6[1] + a7[0]*a7[0] + a7[1]*a7[1];
        ns += __shfl_xor(ns, 1, 64);
        ns += __shfl_xor(ns, 2, 64);
        float inv = 1.0f / fmaxf(sqrtf(ns), 1e-12f);
        if (valid) {
            int r = first ? g : g - n1;
            // fp16 feature copy: [users | items | bundles]
            const unsigned* hf =
                first ? hfeat + (size_t)g * 32
                      : ((r < NUv) ? hfeat + (size_t)r * 32
                                   : hfeat + (size_t)(n1 + (r - NUv)) * 32);
            const __half* nrmIn = first ? nrm11 + (size_t)r * DD
                                        : nrm12 + (size_t)r * DD;
            __half* outp = first ? accIL + (size_t)r * DD
                                 : accBL + (size_t)r * DD;
            uint4 fA = *((const uint4*)hf + sub * 2);
            uint4 fB = *((const uint4*)hf + sub * 2 + 1);
            float2 f0 = unpackH2(fA.x), f1 = unpackH2(fA.y);
            float2 f2 = unpackH2(fA.z), f3 = unpackH2(fA.w);
            float2 f4 = unpackH2(fB.x), f5 = unpackH2(fB.y);
            float2 f6 = unpackH2(fB.z), f7 = unpackH2(fB.w);
            uint4 nvA = *((const uint4*)nrmIn + sub * 2);
            uint4 nvB = *((const uint4*)nrmIn + sub * 2 + 1);
            float2 m0 = unpackH2(nvA.x), m1 = unpackH2(nvA.y);
            float2 m2 = unpackH2(nvA.z), m3 = unpackH2(nvA.w);
            float2 m4 = unpackH2(nvB.x), m5 = unpackH2(nvB.y);
            float2 m6 = unpackH2(nvB.z), m7 = unpackH2(nvB.w);
            uint4 oA, oB;
            oA.x = packH2(f0.x + m0.x + a0[0]*inv, f0.y + m0.y + a0[1]*inv);
            oA.y = packH2(f1.x + m1.x + a1[0]*inv, f1.y + m1.y + a1[1]*inv);
            oA.z = packH2(f2.x + m2.x + a2[0]*inv, f2.y + m2.y + a2[1]*inv);
            oA.w = packH2(f3.x + m3.x + a3[0]*inv, f3.y + m3.y + a3[1]*inv);
            oB.x = packH2(f4.x + m4.x + a4[0]*inv, f4.y + m4.y + a4[1]*inv);
            oB.y = packH2(f5.x + m5.x + a5[0]*inv, f5.y + m5.y + a5[1]*inv);
            oB.z = packH2(f6.x + m6.x + a6[0]*inv, f6.y + m6.y + a6[1]*inv);
            oB.w = packH2(f7.x + m7.x + a7[0]*inv, f7.y + m7.y + a7[1]*inv);
            *((uint4*)outp + sub * 2)     = oA;
            *((uint4*)outp + sub * 2 + 1) = oB;
        }
    }
}

// Graph 3 aggregation (fp16 table), 8 rows/wave, pipelined x4:
// out = u/(deg+1e-8)
__global__ void __launch_bounds__(256) spmm_agg(
    const int* __restrict__ rowStart, const int* __restrict__ cnt,
    const int* __restrict__ cs, int rbase,
    const __half* __restrict__ table16, __half* __restrict__ out16, int n)
{
    int lane = threadIdx.x & 63;
    int grp  = lane >> 3;
    int sub  = lane & 7;
    int wave = (blockIdx.x * blockDim.x + threadIdx.x) >> 6;
    int nW   = (gridDim.x * blockDim.x) >> 6;
    for (int r0 = wave * 8; r0 < n; r0 += nW * 8) {
        int r = r0 + grp;
        bool valid = r < n;
        int idx = rbase + (valid ? r : n - 1);
        int start = rowStart[idx];
        int deg   = valid ? cnt[idx] : 0;
        const int* csp = cs + start;
        v2f a0 = {0.f, 0.f}, a1 = {0.f, 0.f}, a2 = {0.f, 0.f}, a3 = {0.f, 0.f};
        if (deg > 0) {
            int c0 = csp[0];
            int c1i = (1 < deg) ? csp[1] : 0;
            int c2i = (2 < deg) ? csp[2] : 0;
            int c3i = (3 < deg) ? csp[3] : 0;
            int kc = 0, k = 4;
            while (true) {
                uint4 d0 = *((const uint4*)(table16 + (size_t)c0 * DD) + sub);
                uint4 d1 = *((const uint4*)(table16 + (size_t)c1i * DD) + sub);
                uint4 d2 = *((const uint4*)(table16 + (size_t)c2i * DD) + sub);
                uint4 d3 = *((const uint4*)(table16 + (size_t)c3i * DD) + sub);
                bool more = k < deg;
                int n0 = 0, n1v = 0, n2v = 0, n3v = 0;
                if (more) {
                    n0  = csp[k];
                    n1v = (k + 1 < deg) ? csp[k + 1] : 0;
                    n2v = (k + 2 < deg) ? csp[k + 2] : 0;
                    n3v = (k + 3 < deg) ? csp[k + 3] : 0;
                }
                if (kc + 1 >= deg) zero4(d1);
                if (kc + 2 >= deg) zero4(d2);
                if (kc + 3 >= deg) zero4(d3);
                accH16(d0, a0, a1, a2, a3);
                accH16(d1, a0, a1, a2, a3);
                accH16(d2, a0, a1, a2, a3);
                accH16(d3, a0, a1, a2, a3);
                if (!more) break;
                c0 = n0; c1i = n1v; c2i = n2v; c3i = n3v;
                kc = k; k += 4;
            }
        }
        float sc2 = 1.0f / ((float)deg + 1e-8f);
        if (valid) {
            uint4 o;
            o.x = packH2(a0[0]*sc2, a0[1]*sc2);
            o.y = packH2(a1[0]*sc2, a1[1]*sc2);
            o.z = packH2(a2[0]*sc2, a2[1]*sc2);
            o.w = packH2(a3[0]*sc2, a3[1]*sc2);
            *((uint4*)(out16 + (size_t)r * DD) + sub) = o;
        }
    }
}

// ------------------------- batch + losses -------------------------

__global__ void batch_kernel(
    const int* __restrict__ users, const int* __restrict__ bundles,
    const __half* __restrict__ IL, const __half* __restrict__ ILb,
    const __half* __restrict__ BL, int NUv,
    float* __restrict__ pos1, float* __restrict__ aug1,
    float* __restrict__ pos2, float* __restrict__ aug2,
    float* __restrict__ sums, int batch)
{
    int lane = threadIdx.x & 63;
    int wave = (blockIdx.x * blockDim.x + threadIdx.x) >> 6;
    int nW   = (gridDim.x * blockDim.x) >> 6;
    for (int b = wave; b < batch; b += nW) {
        int u   = users[b];
        int bp  = bundles[2 * b];
        int bn  = bundles[2 * b + 1];
        float ilu  = __half2float(IL [(size_t)u * DD + lane]);
        float blu  = __half2float(BL [(size_t)u * DD + lane]);
        float ilb0 = __half2float(ILb[(size_t)bp * DD + lane]);
        float ilb1 = __half2float(ILb[(size_t)bn * DD + lane]);
        float blb0 = __half2float(BL [(size_t)(NUv + bp) * DD + lane]);
        float blb1 = __half2float(BL [(size_t)(NUv + bn) * DD + lane]);
        float d0 = waveSum(ilu * ilb0 + blu * blb0);
        float d1 = waveSum(ilu * ilb1 + blu * blb1);
        float x  = d1 - d0;
        float sp = fmaxf(x, 0.f) + log1pf(expf(-fabsf(x)));
        if (lane == 0) atomicAdd(&sums[0], sp);
        float nilu = sqrtf(waveSum(ilu * ilu));
        float nblu = sqrtf(waveSum(blu * blu));
        float nilb = sqrtf(waveSum(ilb0 * ilb0));
        float nblb = sqrtf(waveSum(blb0 * blb0));
        pos1[(size_t)b * DD + lane] = ilu  / fmaxf(nilu, 1e-12f);
        aug1[(size_t)b * DD + lane] = blu  / fmaxf(nblu, 1e-12f);
        pos2[(size_t)b * DD + lane] = ilb0 / fmaxf(nilb, 1e-12f);
        aug2[(size_t)b * DD + lane] = blb0 / fmaxf(nblb, 1e-12f);
    }
}

__device__ __forceinline__ void load_tile_T(const float* __restrict__ src, int rowBase,
                                            int batch, float* __restrict__ dst, int tx) {
    int i = tx >> 2, c = tx & 3;
#pragma unroll
    for (int t = 0; t < 4; t++) {
        int k0 = c * 4 + t * 16;
        float4 v = make_float4(0.f, 0.f, 0.f, 0.f);
        int gi = rowBase + i;
        if (gi < batch) v = *(const float4*)&src[(size_t)gi * DD + k0];
        dst[(k0 + 0) * 68 + i] = v.x;
        dst[(k0 + 1) * 68 + i] = v.y;
        dst[(k0 + 2) * 68 + i] = v.z;
        dst[(k0 + 3) * 68 + i] = v.w;
    }
}

__global__ void closs_kernel(
    const float* __restrict__ pos1, const float* __restrict__ aug1,
    const float* __restrict__ pos2, const float* __restrict__ aug2,
    float* __restrict__ S, float* __restrict__ Dg, int batch, int jChunk)
{
    const float* pos = blockIdx.z ? pos2 : pos1;
    const float* aug = blockIdx.z ? aug2 : aug1;
    __shared__ float Pt[64 * 68];
    __shared__ float At[64 * 68];
    __shared__ float red[64 * 17];
    int tx = threadIdx.x;
    int iBase = blockIdx.x * 64;
    int jBeg = blockIdx.y * jChunk;
    int jEnd = min(jBeg + jChunk, batch);
    load_tile_T(pos, iBase, batch, Pt, tx);
    int tr = tx >> 4, tc = tx & 15;
    float rs[4] = {0.f, 0.f, 0.f, 0.f};
    for (int j0 = jBeg; j0 < jEnd; j0 += 64) {
        __syncthreads();
        load_tile_T(aug, j0, batch, At, tx);
        __syncthreads();
        float acc[16];
#pragma unroll
        for (int q = 0; q < 16; q++) acc[q] = 0.f;
#pragma unroll 8
        for (int k = 0; k < 64; k++) {
            float4 pv = *(const float4*)&Pt[k * 68 + 4 * tr];
            float4 av = *(const float4*)&At[k * 68 + 4 * tc];
            acc[0]  += pv.x * av.x;  acc[1]  += pv.x * av.y;
            acc[2]  += pv.x * av.z;  acc[3]  += pv.x * av.w;
            acc[4]  += pv.y * av.x;  acc[5]  += pv.y * av.y;
            acc[6]  += pv.y * av.z;  acc[7]  += pv.y * av.w;
            acc[8]  += pv.z * av.x;  acc[9]  += pv.z * av.y;
            acc[10] += pv.z * av.z;  acc[11] += pv.z * av.w;
            acc[12] += pv.w * av.x;  acc[13] += pv.w * av.y;
            acc[14] += pv.w * av.z;  acc[15] += pv.w * av.w;
        }
#pragma unroll
        for (int qi = 0; qi < 4; qi++) {
            int gi = iBase + 4 * tr + qi;
#pragma unroll
            for (int qj = 0; qj < 4; qj++) {
                int gj = j0 + 4 * tc + qj;
                float t = acc[qi * 4 + qj] * INV_TEMP;
                if (gi < batch && gj < batch) {
                    rs[qi] += __expf(t);
                    if (gi == gj) Dg[blockIdx.z * batch + gi] = t;
                }
            }
        }
    }
    __syncthreads();
#pragma unroll
    for (int qi = 0; qi < 4; qi++) red[(4 * tr + qi) * 17 + tc] = rs[qi];
    __syncthreads();
    if (tx < 64) {
        float s = 0.f;
#pragma unroll
        for (int c = 0; c < 16; c++) s += red[tx * 17 + c];
        int gi = iBase + tx;
        if (gi < batch) atomicAdd(&S[blockIdx.z * batch + gi], s);
    }
}

__global__ void closs_finish(const float* __restrict__ S, const float* __restrict__ Dg,
                             const float* __restrict__ sums,
                             float* __restrict__ out, int batch, float invB)
{
    int tid = threadIdx.x;
    __shared__ float wsm[2][4];
    float tot[2];
#pragma unroll
    for (int m = 0; m < 2; m++) {
        float local = 0.f;
        for (int i = tid; i < batch; i += blockDim.x)
            local += logf(S[m * batch + i]) - Dg[m * batch + i];
        local = waveSum(local);
        if ((tid & 63) == 0) wsm[m][tid >> 6] = local;
    }
    __syncthreads();
    if (tid == 0) {
#pragma unroll
        for (int m = 0; m < 2; m++)
            tot[m] = wsm[m][0] + wsm[m][1] + wsm[m][2] + wsm[m][3];
        out[0] = sums[0] * invB;
        out[1] = 0.5f * (tot[0] + tot[1]) * invB;
    }
}

// ------------------------- driver -------------------------

extern "C" void kernel_launch(void* const* d_in, const int* in_sizes, int n_in,
                              void* d_out, int out_size, void* d_ws, size_t ws_size,
                              hipStream_t stream)
{
    const float* usersF = (const float*)d_in[0];
    const float* itemsF = (const float*)d_in[1];
    const float* bundF  = (const float*)d_in[2];
    const int*   il_row = (const int*)d_in[3];
    const int*   il_col = (const int*)d_in[4];
    const int*   bl_row = (const int*)d_in[6];
    const int*   bl_col = (const int*)d_in[7];
    const int*   agg_row = (const int*)d_in[9];
    const int*   agg_col = (const int*)d_in[10];
    const int*   users   = (const int*)d_in[12];
    const int*   bundles = (const int*)d_in[13];

    const int NUv = in_sizes[0] / DD;
    const int NIv = in_sizes[1] / DD;
    const int NBv = in_sizes[2] / DD;
    const int E1 = in_sizes[3], E2 = in_sizes[6], E3 = in_sizes[9];
    const int batch = in_sizes[12];
    const int n1 = NUv + NIv;
    const int n2 = NUv + NBv;
    const int ntot = n1 + n2 + NBv;
    const int Etot = E1 + E2 + E3;
    const int nbins = (ntot + 255) >> BINSHIFT;

    float* ws = (float*)d_ws;
    size_t off = 0;
    float* sums = ws + off;      off += 16;
    float* S    = ws + off;      off += (size_t)2 * batch;
    float* Dg   = ws + off;      off += (size_t)2 * batch;
    float* pos1 = ws + off;      off += (size_t)batch * DD;
    float* aug1 = ws + off;      off += (size_t)batch * DD;
    float* pos2 = ws + off;      off += (size_t)batch * DD;
    float* aug2 = ws + off;      off += (size_t)batch * DD;
    int*   cnt  = (int*)(ws + off);      off += (size_t)ntot;
    int*   rowStart = (int*)(ws + off);  off += (size_t)ntot;
    int*   binCursor = (int*)(ws + off); off += MAXBINS;
    off = (off + 3) & ~(size_t)3;     // 16B align for fp8 tables (uint4 gathers)
    unsigned* binned = (unsigned*)(ws + off); off += (size_t)nbins * CAP;
    unsigned* g01 = (unsigned*)(ws + off); off += (size_t)n1 * 16;
    unsigned* g11 = (unsigned*)(ws + off); off += (size_t)n1 * 16;
    unsigned* g02 = (unsigned*)(ws + off); off += (size_t)n2 * 16;
    unsigned* g12 = (unsigned*)(ws + off); off += (size_t)n2 * 16;
    unsigned* hfeat = (unsigned*)(ws + off); off += (size_t)(n1 + NBv) * 32;
    off = (off + 3) & ~(size_t)3;     // 16B align for half tables
    __half* hbase = (__half*)(ws + off);
    size_t hoff = 0;
    __half* nrm11 = hbase + hoff;  hoff += (size_t)n1 * DD;
    __half* accIL = hbase + hoff;  hoff += (size_t)n1 * DD;
    __half* nrm12 = hbase + hoff;  hoff += (size_t)n2 * DD;
    __half* accBL = hbase + hoff;  hoff += (size_t)n2 * DD;
    __half* ILb   = hbase + hoff;  hoff += (size_t)NBv * DD;
    (void)ws_size;

    hipMemsetAsync(sums, 0, 16 * sizeof(float), stream);
    hipMemsetAsync(S, 0, (size_t)2 * batch * sizeof(float), stream);
    hipMemsetAsync(binCursor, 0, MAXBINS * sizeof(int), stream);

    // ---- binned CSR build (single-pass binA; column-block-sorted binB) ----
    int nA = (Etot + ECAP_A * 1024 - 1) / (ECAP_A * 1024);
    if (nA < 256) nA = 256;
    int chunk = (Etot + nA - 1) / nA;
    binA_kernel<<<nA, 1024, 0, stream>>>(
        il_row, il_col, bl_row, bl_col, agg_row, agg_col,
        E1, E2, E3, n1, n1 + n2, nbins, binCursor, binned, chunk, Etot);
    binB_kernel<<<nbins, 512, 0, stream>>>(
        binned, binCursor, ntot, cnt, rowStart);

    // ---- streaming prep: fp8 tables + fp16 feature copy (needs cnt) ----
    prep_kernel<<<2048, 256, 0, stream>>>(
        usersF, itemsF, bundF, cnt, NUv, NIv, NBv, n1, g01, g02, hfeat);

    const int* cs = (const int*)binned;
    const int nAll = n1 + n2;

    // 16 rows per wave, 4 waves per block -> 64 rows per block
    auto grid16 = [](int n) { return (n + 63) / 64; };
    auto grid8  = [](int n) { return (n + 31) / 32; };

    // ---- layer 1 (graphs 1+2 merged) ----
    spmm_l1<<<grid16(nAll), 256, 0, stream>>>(
        rowStart, cnt, cs, n1, nAll, g01, g02, g11, g12, nrm11, nrm12);

    // ---- layer 2 (graphs 1+2 merged) ----
    spmm_l2<<<grid16(nAll), 256, 0, stream>>>(
        rowStart, cnt, cs, n1, nAll, NUv, g11, g12,
        hfeat, nrm11, nrm12, accIL, accBL);

    // ---- bundle rep from items (graph 3, fp16 table) ----
    spmm_agg<<<grid8(NBv), 256, 0, stream>>>(
        rowStart, cnt, cs, n1 + n2, accIL + (size_t)NUv * DD, ILb, NBv);

    // ---- batch: BPR + normalized gathers ----
    batch_kernel<<<(batch + 3) / 4, 256, 0, stream>>>(
        users, bundles, accIL, ILb, accBL, NUv,
        pos1, aug1, pos2, aug2, sums, batch);

    // ---- contrastive loss ----
    const int yChunks = 8;
    int jChunk = ((batch + yChunks * 64 - 1) / (yChunks * 64)) * 64;
    dim3 cg2((batch + 63) / 64, yChunks, 2);
    closs_kernel<<<cg2, 256, 0, stream>>>(pos1, aug1, pos2, aug2, S, Dg, batch, jChunk);
    closs_finish<<<1, 256, 0, stream>>>(S, Dg, sums, (float*)d_out, batch,
                                        1.0f / (float)batch);
}